// Round 5
// baseline (315.483 us; speedup 1.0000x reference)
//
#include <hip/hip_runtime.h>

constexpr int Dd = 128, Hh = 128, Ww = 128;
constexpr int B_ = 2, L_ = 8;
constexpr int S_SP = Dd * Hh * Ww;          // 2097152
constexpr float CLAMP_MIN = 0.071f;
constexpr float EPS = 1e-5f;

constexpr int DCH = 8;                      // d planes per block
constexpr int NDC = Dd / DCH;               // 16
constexpr int HG = 4;                       // h rows per block
constexpr int NHG = Hh / HG;                // 32
constexpr int BLK_PER_B = NHG * NDC;        // 512
constexpr int NBLK = B_ * BLK_PER_B;        // 1024

// One kernel: softmax over L (inline, from raw pred) + clamp + rolling 27-pt
// box stencil over d + dice partials. No scratch tensor, no hot-loop barriers.
// Block = (b, 4-row h-group, 8-plane d-chunk). 256 thr = 64 w-lanes(x2w) x 4 h.
__global__ __launch_bounds__(256) void fused_all_kernel(
    const float* __restrict__ pred, const float* __restrict__ tgt,
    float* __restrict__ partial) {
  int blk = blockIdx.x;
  int dc = blk & 15;
  int hg = (blk >> 4) & 31;
  int b  = blk >> 9;
  int tid = threadIdx.x;
  int wl = tid & 63;          // w-lane within wave (wave = one h row)
  int hl = tid >> 6;          // 0..3
  int h = hg * HG + hl;
  int w0 = wl * 2;
  int d0 = dc * DCH;
  const float* pb = pred + (size_t)b * L_ * S_SP;
  const float* tb = tgt  + (size_t)b * L_ * S_SP;
  int hm = (h == 0) ? 1 : h - 1;
  int hp = (h == Hh - 1) ? Hh - 2 : h + 1;
  int rows[3] = {hm, h, hp};

  float s2m[L_][2], s2c[L_][2], cprev[L_][2], rawm[L_][2];
  float top[L_], bot[L_];
#pragma unroll
  for (int l = 0; l < L_; ++l) { top[l] = 0.f; bot[l] = 0.f; }

  for (int t = d0 - 1; t <= d0 + DCH; ++t) {
    int rt = t < 0 ? 1 : (t > Dd - 1 ? Dd - 2 : t);
    const float* plane = pb + (size_t)rt * Hh * Ww;
    float s2n[L_][2], ctr[L_][2], rawn[L_][2];
#pragma unroll
    for (int l = 0; l < L_; ++l) { s2n[l][0] = 0.f; s2n[l][1] = 0.f; }

#pragma unroll
    for (int ri = 0; ri < 3; ++ri) {
      const float* rp = plane + rows[ri] * Ww + w0;
      float f0[L_], f1[L_];
#pragma unroll
      for (int l = 0; l < L_; ++l) {
        float2 v = *(const float2*)(rp + (size_t)l * S_SP);
        f0[l] = v.x; f1[l] = v.y;
      }
      // inline softmax + clamp for both w positions
      float p0[L_], p1[L_];
      {
        float m0 = f0[0], m1 = f1[0];
#pragma unroll
        for (int l = 1; l < L_; ++l) { m0 = fmaxf(m0, f0[l]); m1 = fmaxf(m1, f1[l]); }
        float s0 = 0.f, s1 = 0.f;
#pragma unroll
        for (int l = 0; l < L_; ++l) {
          p0[l] = __expf(f0[l] - m0); s0 += p0[l];
          p1[l] = __expf(f1[l] - m1); s1 += p1[l];
        }
        float i0 = 1.f / s0, i1 = 1.f / s1;
#pragma unroll
        for (int l = 0; l < L_; ++l) {
          p0[l] = fmaxf(p0[l] * i0, CLAMP_MIN);
          p1[l] = fmaxf(p1[l] * i1, CLAMP_MIN);
        }
      }
      if (ri == 1) {
#pragma unroll
        for (int l = 0; l < L_; ++l) {
          rawn[l][0] = f0[l]; rawn[l][1] = f1[l];   // raw pred for dice
          ctr[l][0] = p0[l];  ctr[l][1] = p1[l];    // clamped prob center
        }
      }
      // w-neighbor exchange within the wave (wave = one h row)
#pragma unroll
      for (int l = 0; l < L_; ++l) {
        float lf = __shfl_up(p1[l], 1, 64);
        if (wl == 0) lf = p1[l];        // w=-1 reflects to w=1 (own f1)
        float rg = __shfl_down(p0[l], 1, 64);
        if (wl == 63) rg = p0[l];       // w=128 reflects to w=126 (own f0)
        s2n[l][0] += lf + p0[l] + p1[l];
        s2n[l][1] += p0[l] + p1[l] + rg;
      }
    }

    if (t >= d0 + 1) {
      int d = t - 1;
      const float* trow = tb + (size_t)d * Hh * Ww + (size_t)h * Ww + w0;
#pragma unroll
      for (int l = 0; l < L_; ++l) {
        float2 tv = *(const float2*)(trow + (size_t)l * S_SP);
        float bt0 = fabsf(27.f * cprev[l][0] - (s2m[l][0] + s2c[l][0] + s2n[l][0]));
        float bt1 = fabsf(27.f * cprev[l][1] - (s2m[l][1] + s2c[l][1] + s2n[l][1]));
        float bw0 = 0.5f / (bt0 + 0.5f);
        float bw1 = 0.5f / (bt1 + 0.5f);
        top[l] += tv.x * rawm[l][0] * bw0 + tv.y * rawm[l][1] * bw1;
        bot[l] += (tv.x + rawm[l][0]) * bw0 + (tv.y + rawm[l][1]) * bw1;
      }
    }
#pragma unroll
    for (int l = 0; l < L_; ++l) {
      s2m[l][0] = s2c[l][0]; s2m[l][1] = s2c[l][1];
      s2c[l][0] = s2n[l][0]; s2c[l][1] = s2n[l][1];
      cprev[l][0] = ctr[l][0]; cprev[l][1] = ctr[l][1];
      rawm[l][0] = rawn[l][0]; rawm[l][1] = rawn[l][1];
    }
  }

  // ---- block reduction: 8 labels x (top,bot) ----
#pragma unroll
  for (int l = 0; l < L_; ++l) {
#pragma unroll
    for (int o = 32; o > 0; o >>= 1) {
      top[l] += __shfl_down(top[l], o, 64);
      bot[l] += __shfl_down(bot[l], o, 64);
    }
  }
  __shared__ float red[4][16];
  int lane = tid & 63, wv = tid >> 6;
  if (lane == 0) {
#pragma unroll
    for (int l = 0; l < L_; ++l) { red[wv][l * 2] = top[l]; red[wv][l * 2 + 1] = bot[l]; }
  }
  __syncthreads();
  if (tid < 16) {
    float v = red[0][tid] + red[1][tid] + red[2][tid] + red[3][tid];
    partial[blk * 16 + tid] = v;   // [block][l*2 + (0=top,1=bot)]
  }
}

// ---------------- finalize: 1024 x 16 partials -> scalar ----------------
__global__ void finalize_kernel(const float* __restrict__ partial, float* __restrict__ out) {
  __shared__ float rr[16];
  int t = threadIdx.x;             // 256 = 16 (b,l)-pairs x 16 workers
  int p = t >> 4, k = t & 15;
  int b = p >> 3, l = p & 7;
  float top = 0.f, bot = 0.f;
  for (int m = 0; m < BLK_PER_B / 16; ++m) {     // 32 blocks each
    int blk = b * BLK_PER_B + k * (BLK_PER_B / 16) + m;
    top += partial[blk * 16 + l * 2];
    bot += partial[blk * 16 + l * 2 + 1];
  }
#pragma unroll
  for (int o = 8; o > 0; o >>= 1) {
    top += __shfl_down(top, o, 16);
    bot += __shfl_down(bot, o, 16);
  }
  if (k == 0) rr[p] = 2.f * top / fmaxf(bot, EPS);
  __syncthreads();
  if (t == 0) {
    float s = 0.f;
#pragma unroll
    for (int i = 0; i < 16; ++i) s += rr[i];
    out[0] = -s / 16.f;
  }
}

extern "C" void kernel_launch(void* const* d_in, const int* in_sizes, int n_in,
                              void* d_out, int out_size, void* d_ws, size_t ws_size,
                              hipStream_t stream) {
  const float* pred = (const float*)d_in[0];
  const float* tgt  = (const float*)d_in[1];
  float* partial = (float*)d_ws;   // NBLK*16 floats = 64 KB

  fused_all_kernel<<<NBLK, 256, 0, stream>>>(pred, tgt, partial);
  finalize_kernel<<<1, 256, 0, stream>>>(partial, (float*)d_out);
}

// Round 6
// 310.599 us; speedup vs baseline: 1.0157x; 1.0157x over previous
//
#include <hip/hip_runtime.h>
#include <hip/hip_fp16.h>

constexpr int Dd = 128, Hh = 128, Ww = 128;
constexpr int B_ = 2, L_ = 8;
constexpr int S_SP = Dd * Hh * Ww;          // 2097152
constexpr float CLAMP_MIN = 0.071f;
constexpr float EPS = 1e-5f;

constexpr int DCH = 8;                       // d planes per K2 block
constexpr int NDC = Dd / DCH;                // 16
constexpr int NHG = Hh / 16;                 // 8
constexpr int BLK_PER_P = NDC * NHG;         // 128 blocks per (b,l)
constexpr int NBLK2 = B_ * L_ * BLK_PER_P;   // 2048

// ---------------- K1: softmax over L + clamp -> fp16 scratch ----------------
__global__ __launch_bounds__(256) void softmax_fp16_kernel(
    const float* __restrict__ pred, __half* __restrict__ ps) {
  const int S4 = S_SP / 4;
  int g = blockIdx.x * 256 + threadIdx.x;    // over B_*S4
  int b = g / S4;
  int s4 = g - b * S4;
  const float4* in = (const float4*)(pred + (size_t)b * L_ * S_SP) + s4;
  float v[L_][4];
#pragma unroll
  for (int l = 0; l < L_; ++l) {
    float4 t = in[(size_t)l * S4];
    v[l][0] = t.x; v[l][1] = t.y; v[l][2] = t.z; v[l][3] = t.w;
  }
#pragma unroll
  for (int c = 0; c < 4; ++c) {
    float m = v[0][c];
#pragma unroll
    for (int l = 1; l < L_; ++l) m = fmaxf(m, v[l][c]);
    float s = 0.f;
#pragma unroll
    for (int l = 0; l < L_; ++l) { v[l][c] = __expf(v[l][c] - m); s += v[l][c]; }
    float inv = 1.f / s;
#pragma unroll
    for (int l = 0; l < L_; ++l) v[l][c] = fmaxf(v[l][c] * inv, CLAMP_MIN);
  }
#pragma unroll
  for (int l = 0; l < L_; ++l) {
    __half2 h0 = __floats2half2_rn(v[l][0], v[l][1]);
    __half2 h1 = __floats2half2_rn(v[l][2], v[l][3]);
    uint2 u;
    u.x = *(unsigned*)&h0;
    u.y = *(unsigned*)&h1;
    *(uint2*)(ps + ((size_t)(b * L_ + l)) * S_SP + (size_t)s4 * 4) = u;
  }
}

// -------- K2: stencil + dice, software-pipelined (double-buffered) over d --------
// Block = (b,l, 16-row h-group, 8-plane d-chunk). Thread owns 8 w of one h row.
// Plane t+2's row loads and output d=t's dice loads are issued one step before
// consumption; ping-pong buffers break the WAR hazard so loads fly during compute.
__global__ __launch_bounds__(256) void stencil_dice_kernel(
    const __half* __restrict__ ps, const float* __restrict__ pred,
    const float* __restrict__ tgt, float* __restrict__ partial) {
  int blk = blockIdx.x;
  int dc = blk & 15;
  int hg = (blk >> 4) & 7;
  int bl = blk >> 7;                 // b*L + l
  int tid = threadIdx.x;
  int wl = tid & 15, hl = tid >> 4;
  int h = hg * 16 + hl;
  int w0 = wl * 8;
  int d0 = dc * DCH;
  const __half* P = ps + (size_t)bl * S_SP;
  int hm = (h == 0) ? 1 : h - 1;
  int hp = (h == Hh - 1) ? Hh - 2 : h + 1;
  int rows[3] = {hm, h, hp};

  float s2m[8], s2c[8], cprev[8];
  float top = 0.f, bot = 0.f;

  uint4  ubuf[2][3];
  float4 dbuf[2][4];

  auto loadPlane = [&](int t, uint4 u[3]) {
    int rt = t < 0 ? 1 : (t > Dd - 1 ? Dd - 2 : t);
    const __half* plane = P + (size_t)rt * Hh * Ww;
#pragma unroll
    for (int ri = 0; ri < 3; ++ri)
      u[ri] = *(const uint4*)(plane + rows[ri] * Ww + w0);
  };
  auto loadDice = [&](int d, float4 dv[4]) {
    size_t off = (size_t)bl * S_SP + (size_t)d * Hh * Ww + (size_t)h * Ww + w0;
    dv[0] = *(const float4*)(pred + off);
    dv[1] = *(const float4*)(pred + off + 4);
    dv[2] = *(const float4*)(tgt + off);
    dv[3] = *(const float4*)(tgt + off + 4);
  };

  loadPlane(d0 - 1, ubuf[0]);
  loadPlane(d0,     ubuf[1]);

#pragma unroll
  for (int k = 0; k < DCH + 2; ++k) {        // planes t = d0-1 .. d0+8
    int t = d0 - 1 + k;
    // ---- compute 3x3 2D sums for plane t from prefetched regs ----
    float s2n[8], ctr[8];
#pragma unroll
    for (int w = 0; w < 8; ++w) s2n[w] = 0.f;
#pragma unroll
    for (int ri = 0; ri < 3; ++ri) {
      uint4 u = ubuf[k & 1][ri];
      float f[8];
      __half2 a;
      a = *(__half2*)&u.x; { float2 q = __half22float2(a); f[0] = q.x; f[1] = q.y; }
      a = *(__half2*)&u.y; { float2 q = __half22float2(a); f[2] = q.x; f[3] = q.y; }
      a = *(__half2*)&u.z; { float2 q = __half22float2(a); f[4] = q.x; f[5] = q.y; }
      a = *(__half2*)&u.w; { float2 q = __half22float2(a); f[6] = q.x; f[7] = q.y; }
      float lf = __shfl_up(f[7], 1, 64);
      if (wl == 0) lf = f[1];          // w=-1 reflects to w=1
      float rg = __shfl_down(f[0], 1, 64);
      if (wl == 15) rg = f[6];         // w=128 reflects to w=126
      s2n[0] += lf + f[0] + f[1];
#pragma unroll
      for (int w = 1; w < 7; ++w) s2n[w] += f[w - 1] + f[w] + f[w + 1];
      s2n[7] += f[6] + f[7] + rg;
      if (ri == 1) {
#pragma unroll
        for (int w = 0; w < 8; ++w) ctr[w] = f[w];
      }
    }
    // ---- emit output d = t-1 (dice regs prefetched at step k-1) ----
    if (k >= 2) {
      const float4* dv = dbuf[(k + 1) & 1];
      float pv[8] = {dv[0].x, dv[0].y, dv[0].z, dv[0].w, dv[1].x, dv[1].y, dv[1].z, dv[1].w};
      float tv[8] = {dv[2].x, dv[2].y, dv[2].z, dv[2].w, dv[3].x, dv[3].y, dv[3].z, dv[3].w};
#pragma unroll
      for (int w = 0; w < 8; ++w) {
        float bt = fabsf(27.f * cprev[w] - (s2m[w] + s2c[w] + s2n[w]));
        float bw = 0.5f / (bt + 0.5f);
        top += tv[w] * pv[w] * bw;
        bot += (tv[w] + pv[w]) * bw;
      }
    }
#pragma unroll
    for (int w = 0; w < 8; ++w) { s2m[w] = s2c[w]; s2c[w] = s2n[w]; cprev[w] = ctr[w]; }
    // ---- prefetch: plane t+2 into the buffer just consumed; dice row d=t ----
    if (k + 2 <= DCH + 1) loadPlane(t + 2, ubuf[k & 1]);
    if (k >= 1 && k <= DCH) loadDice(t, dbuf[k & 1]);
  }

  // block reduce (2 scalars) -> partial[blk]
#pragma unroll
  for (int o = 32; o > 0; o >>= 1) {
    top += __shfl_down(top, o, 64);
    bot += __shfl_down(bot, o, 64);
  }
  __shared__ float st[4], sb[4];
  int lane = tid & 63, wv = tid >> 6;
  if (lane == 0) { st[wv] = top; sb[wv] = bot; }
  __syncthreads();
  if (tid == 0) {
    partial[blk * 2 + 0] = st[0] + st[1] + st[2] + st[3];
    partial[blk * 2 + 1] = sb[0] + sb[1] + sb[2] + sb[3];
  }
}

// ---------------- K3: 2048 partial pairs -> scalar ----------------
__global__ void finalize_kernel(const float* __restrict__ partial, float* __restrict__ out) {
  __shared__ float rr[16];
  int t = threadIdx.x;             // 256 = 16 pairs x 16 workers
  int p = t >> 4, k = t & 15;
  float top = 0.f, bot = 0.f;
  for (int m = 0; m < BLK_PER_P / 16; ++m) {   // 8 blocks each
    int blk = p * BLK_PER_P + k * (BLK_PER_P / 16) + m;
    top += partial[blk * 2 + 0];
    bot += partial[blk * 2 + 1];
  }
#pragma unroll
  for (int o = 8; o > 0; o >>= 1) {
    top += __shfl_down(top, o, 16);
    bot += __shfl_down(bot, o, 16);
  }
  if (k == 0) rr[p] = 2.f * top / fmaxf(bot, EPS);
  __syncthreads();
  if (t == 0) {
    float s = 0.f;
#pragma unroll
    for (int i = 0; i < 16; ++i) s += rr[i];
    out[0] = -s / 16.f;
  }
}

extern "C" void kernel_launch(void* const* d_in, const int* in_sizes, int n_in,
                              void* d_out, int out_size, void* d_ws, size_t ws_size,
                              hipStream_t stream) {
  const float* pred = (const float*)d_in[0];
  const float* tgt  = (const float*)d_in[1];
  __half* ps = (__half*)d_ws;                                  // 67 MB fp16
  float* partial = (float*)((char*)d_ws + (size_t)B_ * L_ * S_SP * sizeof(__half));

  int g1 = (B_ * (S_SP / 4)) / 256;    // 4096 blocks
  softmax_fp16_kernel<<<g1, 256, 0, stream>>>(pred, ps);
  stencil_dice_kernel<<<NBLK2, 256, 0, stream>>>(ps, pred, tgt, partial);
  finalize_kernel<<<1, 256, 0, stream>>>(partial, (float*)d_out);
}